// Round 6
// baseline (48.757 us; speedup 1.0000x reference)
//
#include <hip/hip_runtime.h>
#include <hip/hip_bf16.h>

// Sizes (fixed by the reference)
#define NL 3      // layers
#define NB 128    // batch
#define NO 64     // objects
#define ND 64     // emb dim
#define NQ 32     // preds per pair
#define NP 4032   // 64*63 ordered pairs

typedef __bf16 bf16x8 __attribute__((ext_vector_type(8)));
typedef float  f32x4  __attribute__((ext_vector_type(4)));

__device__ __forceinline__ float sigm(float x) {
  return __builtin_amdgcn_rcpf(1.0f + __expf(-x));
}

__device__ __forceinline__ bf16x8 pack_bf16(const f32x4 a, const f32x4 b) {
  bf16x8 r;
  r[0] = (__bf16)a[0]; r[1] = (__bf16)a[1]; r[2] = (__bf16)a[2]; r[3] = (__bf16)a[3];
  r[4] = (__bf16)b[0]; r[5] = (__bf16)b[1]; r[6] = (__bf16)b[2]; r[7] = (__bf16)b[3];
  return r;
}

// ---------------------------------------------------------------------------
// Kernel 1: precompute (verbatim from round 1 — known good)
// ---------------------------------------------------------------------------
__global__ __launch_bounds__(256) void precomp_k(
    const int* __restrict__ ids, const float* __restrict__ emb,
    const float* __restrict__ W1, const float* __restrict__ b1,
    float* __restrict__ Ut, float* __restrict__ Vt, float* __restrict__ M,
    float* __restrict__ e_out)
{
  const int blk = blockIdx.x, tid = threadIdx.x;

  if (blk < NB) {
    __shared__ int   ids_s[NO];
    __shared__ float psum[4][ND];
    __shared__ float mean_s[ND];
    const int b = blk;
    if (tid < NO) ids_s[tid] = ids[b * NO + tid];
    __syncthreads();

    {
      const int d = tid & 63, ng = tid >> 6;
      float s = 0.f;
#pragma unroll
      for (int nn = 0; nn < 16; ++nn) {
        const int n = ng * 16 + nn;
        const float v = emb[ids_s[n] * ND + d];
        e_out[(b * NO + n) * ND + d] = v;   // exact f32 copy of e
        s += v;
      }
      psum[ng][d] = s;
    }
    __syncthreads();
    if (tid < ND)
      mean_s[tid] = (psum[0][tid] + psum[1][tid] + psum[2][tid] + psum[3][tid]) * (1.0f / 64.0f);
    __syncthreads();

    if (tid < 192) {
      const int l = tid >> 6, d = tid & 63;
      const float* wrow = W1 + (l * ND + d) * 192 + 128;
      float acc = 0.f;
#pragma unroll
      for (int c4 = 0; c4 < 16; ++c4) {
        const f32x4 w = *(const f32x4*)(wrow + c4 * 4);
        const f32x4 m = *(const f32x4*)(&mean_s[c4 * 4]);
        acc += w[0] * m[0] + w[1] * m[1] + w[2] * m[2] + w[3] * m[3];
      }
      M[(l * NB + b) * ND + d] = acc + b1[l * ND + d];
    }
  } else {
    const int idx = blk - NB;
    const int l = idx >> 1, half = idx & 1;
    __shared__ float e_s[NO][68];
    {
      const int o = tid >> 2, c0 = (tid & 3) * 16;
      const float* er = emb + o * ND + c0;
#pragma unroll
      for (int c = 0; c < 16; c += 4)
        *(f32x4*)(&e_s[o][c0 + c]) = *(const f32x4*)(er + c);
    }
    __syncthreads();

    const int d = tid & 63, og = tid >> 6;   // each thread: 16 objects x 1 d
    const float* wrow = W1 + (l * ND + d) * 192 + half * 64;
    float acc[16];
#pragma unroll
    for (int k = 0; k < 16; ++k) acc[k] = 0.f;
#pragma unroll
    for (int c4 = 0; c4 < 16; ++c4) {
      const f32x4 w = *(const f32x4*)(wrow + c4 * 4);
#pragma unroll
      for (int oo = 0; oo < 16; ++oo) {
        const f32x4 e = *(const f32x4*)(&e_s[og * 16 + oo][c4 * 4]);  // broadcast
        acc[oo] += e[0] * w[0] + e[1] * w[1] + e[2] * w[2] + e[3] * w[3];
      }
    }
    float* T = half ? Vt : Ut;
#pragma unroll
    for (int oo = 0; oo < 16; ++oo)
      T[(l * NO + og * 16 + oo) * ND + d] = acc[oo];
  }
}

// ---------------------------------------------------------------------------
// Kernel 2: lean main. grid = 3*128*4 = 1536 (blk = l*512 + b*4 + ic), 256 thr.
// SINGLE CHANGE vs round 5: LDS-transpose epilogue. Each wave writes its
// 16x32 sigmoid tile to a per-wave LDS buffer (row stride 36 floats = 144B,
// linear-equivalent banking), reads back lane-major, and stores 2KB fully
// contiguous per instruction pair (vs half-line-interleaved before).
// ---------------------------------------------------------------------------
__global__ __launch_bounds__(256, 6) void main_k(
    const int* __restrict__ ids, const float* __restrict__ W2,
    const float* __restrict__ b2,
    const float* __restrict__ Ut, const float* __restrict__ Vt,
    const float* __restrict__ M, float* __restrict__ out)
{
  __shared__ float UpM_s[16 * 68];
  __shared__ float Xp_s[4][16 * 36];   // per-wave transpose buffer (144B rows)

  const int tid = threadIdx.x, blk = blockIdx.x;
  const int ic = blk & 3, b = (blk >> 2) & 127, l = blk >> 9;
  const int lane = tid & 63, wave = tid >> 6;
  const int qlo = lane & 15, g = lane >> 4;
  const int rr = lane >> 2, c = lane & 3;   // read-back mapping (lane-major)
  const int i0 = ic * 16;

  // ---- stage UpM: 16 rows x 64 cols, one f32x4 per thread ----
  {
    const int row = tid >> 4, c0 = (tid & 15) * 4;
    const int idi = ids[b * NO + i0 + row];
    const float* u = Ut + (l * NO + idi) * ND + c0;
    const float* m = M + (l * NB + b) * ND + c0;
    *(f32x4*)(&UpM_s[row * 68 + c0]) = *(const f32x4*)u + *(const f32x4*)m;
  }

  // ---- V (f32), W2 frags, b2 into registers (loop-invariant) ----
  const int jA = wave * 16 + qlo;        // this lane's pair column j (fixed)
  const int idj = ids[b * NO + jA];
  const float* vrow = Vt + (l * NO + idj) * ND;
  f32x4 vf[2][2];
#pragma unroll
  for (int kt = 0; kt < 2; ++kt) {
    vf[kt][0] = *(const f32x4*)(vrow + kt * 32 + g * 8);
    vf[kt][1] = *(const f32x4*)(vrow + kt * 32 + g * 8 + 4);
  }
  bf16x8 wfrag[2][2];
#pragma unroll
  for (int qt = 0; qt < 2; ++qt)
#pragma unroll
    for (int kt = 0; kt < 2; ++kt) {
      const float* wp = W2 + (l * NQ + qt * 16 + qlo) * ND + kt * 32 + g * 8;
      wfrag[qt][kt] = pack_bf16(*(const f32x4*)wp, *(const f32x4*)(wp + 4));
    }
  const f32x4 b20 = *(const f32x4*)(b2 + l * NQ + g * 4);        // q = 4g+r
  const f32x4 b21 = *(const f32x4*)(b2 + l * NQ + 16 + g * 4);   // q = 16+4g+r

  __syncthreads();

  float* outb = out + (size_t)(l * NB + b) * NP * NQ;
  float* wb = &Xp_s[wave][0];
  const int jR = wave * 16 + rr;         // read-back row -> pair column j

  // ---- barrier-free i-loop ----
#pragma unroll 2
  for (int ii = 0; ii < 16; ++ii) {
    const float* upm = &UpM_s[ii * 68];
    bf16x8 hb[2];
#pragma unroll
    for (int kt = 0; kt < 2; ++kt) {
      const int k0 = kt * 32 + g * 8;
      const f32x4 r0 = *(const f32x4*)(upm + k0);
      const f32x4 r1 = *(const f32x4*)(upm + k0 + 4);
      f32x4 h0, h1;
#pragma unroll
      for (int e = 0; e < 4; ++e) {
        h0[e] = fmaxf(vf[kt][0][e] + r0[e], 0.0f);
        h1[e] = fmaxf(vf[kt][1][e] + r1[e], 0.0f);
      }
      hb[kt] = pack_bf16(h0, h1);
    }

    const f32x4 z = {0.f, 0.f, 0.f, 0.f};
    // Swapped operands: D[row=q][col=j]; lane holds q = 4g+r, j = qlo+wave*16
    f32x4 acc0 = __builtin_amdgcn_mfma_f32_16x16x32_bf16(wfrag[0][0], hb[0], z, 0, 0, 0);
    acc0 = __builtin_amdgcn_mfma_f32_16x16x32_bf16(wfrag[0][1], hb[1], acc0, 0, 0, 0);
    f32x4 acc1 = __builtin_amdgcn_mfma_f32_16x16x32_bf16(wfrag[1][0], hb[0], z, 0, 0, 0);
    acc1 = __builtin_amdgcn_mfma_f32_16x16x32_bf16(wfrag[1][1], hb[1], acc1, 0, 0, 0);

    f32x4 o0, o1;
#pragma unroll
    for (int r = 0; r < 4; ++r) {
      o0[r] = sigm(acc0[r] + b20[r]);
      o1[r] = sigm(acc1[r] + b21[r]);
    }

    // transpose through per-wave LDS: row = j-local (qlo), cols q
    *(f32x4*)(&wb[qlo * 36 + g * 4]) = o0;        // q = 4g..4g+3
    *(f32x4*)(&wb[qlo * 36 + 16 + g * 4]) = o1;   // q = 16+4g..16+4g+3
    asm volatile("s_waitcnt lgkmcnt(0)" ::: "memory");
    const f32x4 rd0 = *(const f32x4*)(&wb[rr * 36 + c * 8]);
    const f32x4 rd1 = *(const f32x4*)(&wb[rr * 36 + c * 8 + 4]);

    const int i = i0 + ii;
    if (jR != i) {
      const int p = (jR < i) ? jR : jR - 1;
      float* dst = outb + ((size_t)i * 63 + p) * NQ + c * 8;
      *(f32x4*)dst = rd0;          // lane-contiguous: 2KB/wave fully linear
      *(f32x4*)(dst + 4) = rd1;
    }
  }
}

// ---------------------------------------------------------------------------
extern "C" void kernel_launch(void* const* d_in, const int* in_sizes, int n_in,
                              void* d_out, int out_size, void* d_ws, size_t ws_size,
                              hipStream_t stream) {
  const int*   ids = (const int*)d_in[0];
  const float* emb = (const float*)d_in[1];
  const float* W1  = (const float*)d_in[2];
  const float* b1  = (const float*)d_in[3];
  const float* W2  = (const float*)d_in[4];
  const float* b2  = (const float*)d_in[5];
  float* out = (float*)d_out;

  float* Ut = (float*)d_ws;              // [3][64][64] f32
  float* Vt = Ut + NL * NO * ND;         // [3][64][64] f32
  float* M  = Vt + NL * NO * ND;         // [3][128][64] f32  (192 KB of ws)
  float* e_out = out + (size_t)NL * NB * NP * NQ;  // e appended after preds

  precomp_k<<<NB + 2 * NL, 256, 0, stream>>>(ids, emb, W1, b1, Ut, Vt, M, e_out);
  main_k<<<NL * NB * 4, 256, 0, stream>>>(ids, W2, b2, Ut, Vt, M, out);
}

// Round 7
// 43.153 us; speedup vs baseline: 1.1299x; 1.1299x over previous
//
#include <hip/hip_runtime.h>
#include <hip/hip_bf16.h>

// Sizes (fixed by the reference)
#define NL 3      // layers
#define NB 128    // batch
#define NO 64     // objects
#define ND 64     // emb dim
#define NQ 32     // preds per pair
#define NP 4032   // 64*63 ordered pairs

typedef __bf16 bf16x8 __attribute__((ext_vector_type(8)));
typedef float  f32x4  __attribute__((ext_vector_type(4)));

__device__ __forceinline__ float sigm(float x) {
  return __builtin_amdgcn_rcpf(1.0f + __expf(-x));
}

__device__ __forceinline__ bf16x8 pack_bf16(const f32x4 a, const f32x4 b) {
  bf16x8 r;
  r[0] = (__bf16)a[0]; r[1] = (__bf16)a[1]; r[2] = (__bf16)a[2]; r[3] = (__bf16)a[3];
  r[4] = (__bf16)b[0]; r[5] = (__bf16)b[1]; r[6] = (__bf16)b[2]; r[7] = (__bf16)b[3];
  return r;
}

// ---------------------------------------------------------------------------
// Kernel 1: precompute.
//   blocks 0..127   : b -> mean, M[l][b][d] = mean.W1c + b1 ; exact e copy
//   blocks 128..151 : (l, dt) -> one 64x16 strip of Ut (dt<4) or Vt (dt>=4)
//                     via MFMA: one 16x16(xK=64) tile per wave (2 MFMA).
//                     ~100x less work per block than the old 6-block version.
// ---------------------------------------------------------------------------
__global__ __launch_bounds__(256) void precomp_k(
    const int* __restrict__ ids, const float* __restrict__ emb,
    const float* __restrict__ W1, const float* __restrict__ b1,
    float* __restrict__ Ut, float* __restrict__ Vt, float* __restrict__ M,
    float* __restrict__ e_out)
{
  const int blk = blockIdx.x, tid = threadIdx.x;

  if (blk < NB) {
    __shared__ int   ids_s[NO];
    __shared__ float psum[4][ND];
    __shared__ float mean_s[ND];
    const int b = blk;
    if (tid < NO) ids_s[tid] = ids[b * NO + tid];
    __syncthreads();

    {
      const int d = tid & 63, ng = tid >> 6;
      float s = 0.f;
#pragma unroll
      for (int nn = 0; nn < 16; ++nn) {
        const int n = ng * 16 + nn;
        const float v = emb[ids_s[n] * ND + d];
        e_out[(b * NO + n) * ND + d] = v;   // exact f32 copy of e
        s += v;
      }
      psum[ng][d] = s;
    }
    __syncthreads();
    if (tid < ND)
      mean_s[tid] = (psum[0][tid] + psum[1][tid] + psum[2][tid] + psum[3][tid]) * (1.0f / 64.0f);
    __syncthreads();

    if (tid < 192) {
      const int l = tid >> 6, d = tid & 63;
      const float* wrow = W1 + (l * ND + d) * 192 + 128;
      float acc = 0.f;
#pragma unroll
      for (int c4 = 0; c4 < 16; ++c4) {
        const f32x4 w = *(const f32x4*)(wrow + c4 * 4);
        const f32x4 m = *(const f32x4*)(&mean_s[c4 * 4]);
        acc += w[0] * m[0] + w[1] * m[1] + w[2] * m[2] + w[3] * m[3];
      }
      M[(l * NB + b) * ND + d] = acc + b1[l * ND + d];
    }
  } else {
    // ---- table blocks: one (l, d-tile) strip per block, one row-tile/wave ----
    const int lane = tid & 63, wave = tid >> 6;
    const int qlo = lane & 15, g = lane >> 4;
    const int idx = blk - NB;            // 0..23
    const int l = idx >> 3, dt = idx & 7;
    const bool isU = (dt < 4);
    const int dcol = (dt & 3) * 16 + qlo;

    const float* arow = emb + (wave * 16 + qlo) * ND;            // A row = object
    const float* brow = W1 + (l * ND + dcol) * 192 + (isU ? 0 : 64);
    f32x4 acc = {0.f, 0.f, 0.f, 0.f};
#pragma unroll
    for (int kh = 0; kh < 2; ++kh) {
      const int k0 = kh * 32 + g * 8;
      const bf16x8 af = pack_bf16(*(const f32x4*)(arow + k0), *(const f32x4*)(arow + k0 + 4));
      const bf16x8 bf = pack_bf16(*(const f32x4*)(brow + k0), *(const f32x4*)(brow + k0 + 4));
      acc = __builtin_amdgcn_mfma_f32_16x16x32_bf16(af, bf, acc, 0, 0, 0);
    }
    float* T = isU ? Ut : Vt;            // D: row(obj) = wave*16+4g+r, col(d) = dcol
#pragma unroll
    for (int r = 0; r < 4; ++r)
      T[(l * NO + wave * 16 + 4 * g + r) * ND + dcol] = acc[r];
  }
}

// ---------------------------------------------------------------------------
// Kernel 2: lean main (verbatim round 5 — best known: 45.0 us).
// grid = 3*128*4 = 1536 (blk = l*512 + b*4 + ic), 256 thr, 16 i-rows/block.
// ---------------------------------------------------------------------------
__global__ __launch_bounds__(256, 6) void main_k(
    const int* __restrict__ ids, const float* __restrict__ W2,
    const float* __restrict__ b2,
    const float* __restrict__ Ut, const float* __restrict__ Vt,
    const float* __restrict__ M, float* __restrict__ out)
{
  __shared__ float UpM_s[16 * 68];

  const int tid = threadIdx.x, blk = blockIdx.x;
  const int ic = blk & 3, b = (blk >> 2) & 127, l = blk >> 9;
  const int lane = tid & 63, wave = tid >> 6;
  const int qlo = lane & 15, g = lane >> 4;
  const int i0 = ic * 16;

  // ---- stage UpM: 16 rows x 64 cols, one f32x4 per thread ----
  {
    const int row = tid >> 4, c0 = (tid & 15) * 4;
    const int idi = ids[b * NO + i0 + row];
    const float* u = Ut + (l * NO + idi) * ND + c0;
    const float* m = M + (l * NB + b) * ND + c0;
    *(f32x4*)(&UpM_s[row * 68 + c0]) = *(const f32x4*)u + *(const f32x4*)m;
  }

  // ---- V (f32), W2 frags, b2 into registers (loop-invariant) ----
  const int jA = wave * 16 + qlo;        // this lane's pair column j (fixed)
  const int idj = ids[b * NO + jA];
  const float* vrow = Vt + (l * NO + idj) * ND;
  f32x4 vf[2][2];
#pragma unroll
  for (int kt = 0; kt < 2; ++kt) {
    vf[kt][0] = *(const f32x4*)(vrow + kt * 32 + g * 8);
    vf[kt][1] = *(const f32x4*)(vrow + kt * 32 + g * 8 + 4);
  }
  bf16x8 wfrag[2][2];
#pragma unroll
  for (int qt = 0; qt < 2; ++qt)
#pragma unroll
    for (int kt = 0; kt < 2; ++kt) {
      const float* wp = W2 + (l * NQ + qt * 16 + qlo) * ND + kt * 32 + g * 8;
      wfrag[qt][kt] = pack_bf16(*(const f32x4*)wp, *(const f32x4*)(wp + 4));
    }
  const f32x4 b20 = *(const f32x4*)(b2 + l * NQ + g * 4);        // q = 4g+r
  const f32x4 b21 = *(const f32x4*)(b2 + l * NQ + 16 + g * 4);   // q = 16+4g+r

  __syncthreads();

  float* outb = out + (size_t)(l * NB + b) * NP * NQ;

  // ---- barrier-free i-loop (unroll 2 for cross-iter ILP) ----
#pragma unroll 2
  for (int ii = 0; ii < 16; ++ii) {
    const float* upm = &UpM_s[ii * 68];
    bf16x8 hb[2];
#pragma unroll
    for (int kt = 0; kt < 2; ++kt) {
      const int k0 = kt * 32 + g * 8;
      const f32x4 r0 = *(const f32x4*)(upm + k0);
      const f32x4 r1 = *(const f32x4*)(upm + k0 + 4);
      f32x4 h0, h1;
#pragma unroll
      for (int e = 0; e < 4; ++e) {
        h0[e] = fmaxf(vf[kt][0][e] + r0[e], 0.0f);
        h1[e] = fmaxf(vf[kt][1][e] + r1[e], 0.0f);
      }
      hb[kt] = pack_bf16(h0, h1);
    }

    const f32x4 z = {0.f, 0.f, 0.f, 0.f};
    // Swapped operands: D[row=q][col=j]; lane holds q = 4g+r, j = qlo+wave*16
    f32x4 acc0 = __builtin_amdgcn_mfma_f32_16x16x32_bf16(wfrag[0][0], hb[0], z, 0, 0, 0);
    acc0 = __builtin_amdgcn_mfma_f32_16x16x32_bf16(wfrag[0][1], hb[1], acc0, 0, 0, 0);
    f32x4 acc1 = __builtin_amdgcn_mfma_f32_16x16x32_bf16(wfrag[1][0], hb[0], z, 0, 0, 0);
    acc1 = __builtin_amdgcn_mfma_f32_16x16x32_bf16(wfrag[1][1], hb[1], acc1, 0, 0, 0);

    const int i = i0 + ii;
    if (jA != i) {
      const int p = (jA < i) ? jA : jA - 1;
      float* base = outb + ((size_t)i * 63 + p) * NQ + g * 4;
      f32x4 o0, o1;
#pragma unroll
      for (int r = 0; r < 4; ++r) {
        o0[r] = sigm(acc0[r] + b20[r]);
        o1[r] = sigm(acc1[r] + b21[r]);
      }
      *(f32x4*)base = o0;
      *(f32x4*)(base + 16) = o1;
    }
  }
}

// ---------------------------------------------------------------------------
extern "C" void kernel_launch(void* const* d_in, const int* in_sizes, int n_in,
                              void* d_out, int out_size, void* d_ws, size_t ws_size,
                              hipStream_t stream) {
  const int*   ids = (const int*)d_in[0];
  const float* emb = (const float*)d_in[1];
  const float* W1  = (const float*)d_in[2];
  const float* b1  = (const float*)d_in[3];
  const float* W2  = (const float*)d_in[4];
  const float* b2  = (const float*)d_in[5];
  float* out = (float*)d_out;

  float* Ut = (float*)d_ws;              // [3][64][64] f32
  float* Vt = Ut + NL * NO * ND;         // [3][64][64] f32
  float* M  = Vt + NL * NO * ND;         // [3][128][64] f32  (192 KB of ws)
  float* e_out = out + (size_t)NL * NB * NP * NQ;  // e appended after preds

  precomp_k<<<NB + 24, 256, 0, stream>>>(ids, emb, W1, b1, Ut, Vt, M, e_out);
  main_k<<<NL * NB * 4, 256, 0, stream>>>(ids, W2, b2, Ut, Vt, M, out);
}